// Round 7
// baseline (37513.602 us; speedup 1.0000x reference)
//
#include <hip/hip_runtime.h>
#include <math.h>

#define D_MODEL 1024
#define NHEADS 16
#define DHEAD 64
#define NLAYERS 12
#define VOCAB 32000
#define BATCH 8
#define SEQ 512
#define NTOK (BATCH*SEQ)   // 4096

using short8 = __attribute__((ext_vector_type(8))) short;
using fx4    = __attribute__((ext_vector_type(4))) float;

#define GLL16(g, l) __builtin_amdgcn_global_load_lds( \
    (const __attribute__((address_space(1))) unsigned int*)(g), \
    (__attribute__((address_space(3))) unsigned int*)(l), 16, 0, 0)

__device__ __forceinline__ unsigned short f2bf(float f) {
  union { float f; unsigned u; } v; v.f = f;
  unsigned r = v.u + 0x7FFFu + ((v.u >> 16) & 1u);
  return (unsigned short)(r >> 16);
}
__device__ __forceinline__ float bf2f(unsigned short u) {
  union { unsigned u; float f; } v; v.u = ((unsigned)u) << 16;
  return v.f;
}
__device__ __forceinline__ void split2(float x, unsigned short& h, unsigned short& l) {
  h = f2bf(x);
  l = f2bf(x - bf2f(h));
}
__device__ __forceinline__ float gelu_exact(float x) {
  return 0.5f * x * (1.f + erff(x * 0.70710678118654752f));
}

// ---------------- weight conversion (hi/lo split planes) ----------------

__global__ __launch_bounds__(256) void cvt_qkv_split(const float* __restrict__ WQ,
    const float* __restrict__ WK, const float* __restrict__ WV,
    unsigned short* __restrict__ out)
{
  const long total = 12L * 3072 * 256;     // float4 units
  const long stride = (long)gridDim.x * blockDim.x;
  for (long t = (long)blockIdx.x * blockDim.x + threadIdx.x; t < total; t += stride) {
    const long layer = t / (3072L * 256);
    const long rem = t - layer * (3072L * 256);
    const int n = (int)(rem >> 8);
    const int k4 = (int)(rem & 255);
    const float* src;
    if (n < 1024)       src = WQ + ((size_t)layer * 1024 + n) * 1024;
    else if (n < 2048)  src = WK + ((size_t)layer * 1024 + (n - 1024)) * 1024;
    else                src = WV + ((size_t)layer * 1024 + (n - 2048)) * 1024;
    const float4 v = *(const float4*)(src + k4 * 4);
    ushort4 h, l; unsigned short a, b;
    split2(v.x, a, b); h.x = a; l.x = b;
    split2(v.y, a, b); h.y = a; l.y = b;
    split2(v.z, a, b); h.z = a; l.z = b;
    split2(v.w, a, b); h.w = a; l.w = b;
    unsigned short* dst = out + ((size_t)layer * 3072 + n) * 2048 + k4 * 4;
    *(ushort4*)dst = h;
    *(ushort4*)(dst + 1024) = l;
  }
}

__global__ __launch_bounds__(256) void cvt_split(const float* __restrict__ in,
    unsigned short* __restrict__ out, long rows, int K)
{
  const int K4 = K >> 2;
  const long total = rows * K4;
  const long stride = (long)gridDim.x * blockDim.x;
  for (long t = (long)blockIdx.x * blockDim.x + threadIdx.x; t < total; t += stride) {
    const long r = t / K4;
    const int k4 = (int)(t - r * K4);
    const float4 v = *(const float4*)(in + r * K + k4 * 4);
    ushort4 h, l; unsigned short a, b;
    split2(v.x, a, b); h.x = a; l.x = b;
    split2(v.y, a, b); h.y = a; l.y = b;
    split2(v.z, a, b); h.z = a; l.z = b;
    split2(v.w, a, b); h.w = a; l.w = b;
    unsigned short* dst = out + r * 2 * K + k4 * 4;
    *(ushort4*)dst = h;
    *(ushort4*)(dst + K) = l;
  }
}

__global__ __launch_bounds__(256) void transpose_cvt_split(const float* __restrict__ in,
    unsigned short* __restrict__ out, int R, int C)
{
  __shared__ float tile[32][33];
  in  += (size_t)blockIdx.z * R * C;
  out += (size_t)blockIdx.z * 2 * R * C;
  const int r0 = blockIdx.y * 32, c0 = blockIdx.x * 32;
  const int tr = threadIdx.x >> 5, tc = threadIdx.x & 31;
#pragma unroll
  for (int i = 0; i < 4; ++i)
    tile[tr + i * 8][tc] = in[(size_t)(r0 + tr + i * 8) * C + c0 + tc];
  __syncthreads();
#pragma unroll
  for (int i = 0; i < 4; ++i) {
    unsigned short h, l;
    split2(tile[tc][tr + i * 8], h, l);
    const size_t o = (size_t)(c0 + tr + i * 8) * 2 * R + r0 + tc;
    out[o] = h;
    out[o + R] = l;
  }
}

__global__ __launch_bounds__(256) void transpose_cvt(const float* __restrict__ in,
    unsigned short* __restrict__ out, int R, int C)
{
  __shared__ float tile[32][33];
  const int r0 = blockIdx.y * 32, c0 = blockIdx.x * 32;
  const int tr = threadIdx.x >> 5, tc = threadIdx.x & 31;
#pragma unroll
  for (int i = 0; i < 4; ++i)
    tile[tr + i * 8][tc] = in[(size_t)(r0 + tr + i * 8) * C + c0 + tc];
  __syncthreads();
#pragma unroll
  for (int i = 0; i < 4; ++i)
    out[(size_t)(c0 + tr + i * 8) * R + r0 + tc] = f2bf(tile[tc][tr + i * 8]);
}

// ---------------- embedding + positional ----------------

__global__ __launch_bounds__(256) void embed_kernel(const int* __restrict__ ids,
    const float* __restrict__ Wv, float* __restrict__ x)
{
  const int t = blockIdx.x;
  const int id = ids[t];
  const int l = t & (SEQ - 1);
  const float pos = (float)l;
  const int d0 = threadIdx.x * 4;
  const float i0 = (float)(d0 >> 1);
  const float f0 = expf(-0.017988946039016f * i0);
  const float f1 = expf(-0.017988946039016f * (i0 + 1.f));
  const float a0 = pos * f0, a1 = pos * f1;
  float4 v;
  v.x = Wv[(size_t)(d0 + 0) * VOCAB + id] + sinf(a0);
  v.y = Wv[(size_t)(d0 + 1) * VOCAB + id] + cosf(a0);
  v.z = Wv[(size_t)(d0 + 2) * VOCAB + id] + sinf(a1);
  v.w = Wv[(size_t)(d0 + 3) * VOCAB + id] + cosf(a1);
  ((float4*)(x + (size_t)t * 1024))[threadIdx.x] = v;
}

// ---------------- layernorm (f32 in -> hi/lo bf16 planes out, stride 2048) ----------------

__global__ __launch_bounds__(256) void layernorm_split(const float* __restrict__ x,
    const float* __restrict__ g, const float* __restrict__ be,
    unsigned short* __restrict__ out)
{
  const int row = blockIdx.x;
  const float4 v = ((const float4*)(x + (size_t)row * 1024))[threadIdx.x];
  float s = v.x + v.y + v.z + v.w;
  float q = v.x * v.x + v.y * v.y + v.z * v.z + v.w * v.w;
#pragma unroll
  for (int o = 32; o; o >>= 1) { s += __shfl_xor(s, o); q += __shfl_xor(q, o); }
  __shared__ float ss[4], qq[4];
  const int w = threadIdx.x >> 6;
  if ((threadIdx.x & 63) == 0) { ss[w] = s; qq[w] = q; }
  __syncthreads();
  s = ss[0] + ss[1] + ss[2] + ss[3];
  q = qq[0] + qq[1] + qq[2] + qq[3];
  const float mean = s * (1.f / 1024.f);
  const float var = q * (1.f / 1024.f) - mean * mean;
  const float rstd = rsqrtf(var + 1e-5f);
  const float4 gv = ((const float4*)g)[threadIdx.x];
  const float4 bv = ((const float4*)be)[threadIdx.x];
  float4 y;
  y.x = (v.x - mean) * rstd * gv.x + bv.x;
  y.y = (v.y - mean) * rstd * gv.y + bv.y;
  y.z = (v.z - mean) * rstd * gv.z + bv.z;
  y.w = (v.w - mean) * rstd * gv.w + bv.w;
  ushort4 h4, l4; unsigned short a, b;
  split2(y.x, a, b); h4.x = a; l4.x = b;
  split2(y.y, a, b); h4.y = a; l4.y = b;
  split2(y.z, a, b); h4.z = a; l4.z = b;
  split2(y.w, a, b); h4.w = a; l4.w = b;
  unsigned short* dst = out + (size_t)row * 2048 + threadIdx.x * 4;
  *(ushort4*)dst = h4;
  *(ushort4*)(dst + 1024) = l4;
}

// ---------------- split GEMM: C[M,N] = A[M,K] * B[N,K]^T, near-f32 precision ----------------
// global_load_lds width-16 staging (m97 pattern) + bijective XCD swizzle.

template<int EPI, int SPLIT>
__global__ __launch_bounds__(256) void gemm_bt(
    const unsigned short* __restrict__ A, const unsigned short* __restrict__ B,
    float* __restrict__ Cf, unsigned short* __restrict__ Cb,
    const float* __restrict__ bias, const float* __restrict__ res,
    int M, int N, int K)
{
  __shared__ __align__(16) unsigned short As[128 * 64];
  __shared__ __align__(16) unsigned short Bs[128 * 64];
  const int tid = threadIdx.x;
  const int lane = tid & 63, w = tid >> 6;
  const int wr = w >> 1, wc = w & 1;

  // XCD-aware block swizzle (all grids here are %8 == 0 -> bijective)
  const int gx = gridDim.x;
  int wg = blockIdx.y * gx + blockIdx.x;
  {
    const int cpx = (gx * gridDim.y) >> 3;
    wg = (wg & 7) * cpx + (wg >> 3);
  }
  const int brow = (wg / gx) * 128, bcol = (wg % gx) * 128;

  const int SA = 2 * K;                         // A always hi/lo
  const int SB = (SPLIT == 3) ? 2 * K : K;
  const int KEFF = SPLIT * K;
  fx4 acc[4][4];
  const fx4 zero = {0.f, 0.f, 0.f, 0.f};
#pragma unroll
  for (int i = 0; i < 4; ++i)
#pragma unroll
    for (int j = 0; j < 4; ++j) acc[i][j] = zero;

  const unsigned short* Ab = A + (size_t)brow * SA;
  const unsigned short* Bb = B + (size_t)bcol * SB;

  for (int k0 = 0; k0 < KEFF; k0 += 64) {
    int ka, kb;
    if (SPLIT == 3) {
      ka = (k0 < 2 * K) ? k0 : k0 - 2 * K;      // hi | lo | hi
      kb = (k0 < K) ? k0 : k0 - K;              // hi | hi | lo
    } else {
      ka = k0;                                  // hi | lo
      kb = (k0 < K) ? k0 : k0 - K;              // hi | hi
    }
    const unsigned short* Aseg = Ab + ka;
    const unsigned short* Bseg = Bb + kb;
#pragma unroll
    for (int it = 0; it < 4; ++it) {
      const int idx = it * 256 + tid;          // 0..1023
      const int r = idx >> 3, c = (idx & 7) * 8;
      GLL16(&Aseg[(size_t)r * SA + c], &As[idx * 8]);
      GLL16(&Bseg[(size_t)r * SB + c], &Bs[idx * 8]);
    }
    __syncthreads();   // drains vmcnt (global_load_lds) before ds_read
#pragma unroll
    for (int kk = 0; kk < 2; ++kk) {
      short8 af[4], bfv[4];
      const int kof = kk * 32 + (lane >> 4) * 8;
#pragma unroll
      for (int f = 0; f < 4; ++f)
        af[f] = *(const short8*)&As[(wr * 64 + f * 16 + (lane & 15)) * 64 + kof];
#pragma unroll
      for (int f = 0; f < 4; ++f)
        bfv[f] = *(const short8*)&Bs[(wc * 64 + f * 16 + (lane & 15)) * 64 + kof];
#pragma unroll
      for (int i = 0; i < 4; ++i)
#pragma unroll
        for (int j = 0; j < 4; ++j)
          acc[i][j] = __builtin_amdgcn_mfma_f32_16x16x32_bf16(af[i], bfv[j], acc[i][j], 0, 0, 0);
    }
    __syncthreads();
  }

  // C/D layout: col = lane&15, row = (lane>>4)*4 + reg
  const int r0 = brow + wr * 64 + (lane >> 4) * 4;
  const int c0 = bcol + wc * 64 + (lane & 15);
#pragma unroll
  for (int i = 0; i < 4; ++i) {
#pragma unroll
    for (int j = 0; j < 4; ++j) {
      const int cc = c0 + j * 16;
#pragma unroll
      for (int qi = 0; qi < 4; ++qi) {
        const int rr = r0 + i * 16 + qi;
        const size_t off = (size_t)rr * N + cc;
        const float val = acc[i][j][qi];
        if (EPI == 0) {
          Cf[off] = val;
        } else if (EPI == 2) {
          Cf[off] = res[off] + val;
        } else if (EPI == 3) {
          unsigned short hh, ll;
          split2(gelu_exact(val + bias[cc]), hh, ll);
          Cb[(size_t)rr * (2 * N) + cc] = hh;
          Cb[(size_t)rr * (2 * N) + N + cc] = ll;
        } else {
          Cf[off] = res[off] + val + bias[cc];
        }
      }
    }
  }
}

// ---------------- attention v2: flash online softmax, K/V in registers ----------------
// grid.x = B*H*8 ; block = 512 (8 waves). Block: (b, h, 64-row tile).
// Wave: 8 rows (l = row0 + k*8 + w). Scores: lane = key (K regs, q broadcast from LDS).
// PV: lane = d (V regs from coalesced global loads, p broadcast from LDS).
// qkvf: [NTOK][3072] f32 (q|k|v). out2: [NTOK][2048] bf16 hi|lo planes.

__global__ __launch_bounds__(512) void attn_kernel(
    const float* __restrict__ qkvf,
    const int* __restrict__ amask,
    unsigned short* __restrict__ out2)
{
  const int bid = blockIdx.x;
  const int rt = bid & 7;
  const int h  = (bid >> 3) & 15;
  const int b  = bid >> 7;
  const int row0 = rt * 64;

  __shared__ __align__(16) float Kst[128 * 68];     // [key][slot], stride 68 dwords
  __shared__ __align__(16) float q_lds[8][8][64];   // [wave][rowk][d]
  __shared__ __align__(16) float p_lds[8][64];      // [wave][key]

  const int tid = threadIdx.x, lane = tid & 63, w = tid >> 6;
  const size_t base = (size_t)b * SEQ;

  // hoist q rows for this wave into LDS (read-only for rest of kernel)
#pragma unroll
  for (int k = 0; k < 8; ++k) {
    const int l = row0 + k * 8 + w;
    q_lds[w][k][lane] = qkvf[(base + l) * 3072 + h * 64 + lane];
  }

  float m_s[8], sum_s[8], acc_s[8];
#pragma unroll
  for (int k = 0; k < 8; ++k) { m_s[k] = -1e9f; sum_s[k] = 0.f; acc_s[k] = 0.f; }

  const int lastkey = row0 + 63;
  const int nch = (row0 + 191) >> 7;        // 128-key chunks covering 0..lastkey
  for (int ch = 0; ch < nch; ++ch) {
    const int c0 = ch << 7;
    __syncthreads();                        // prev chunk's reg loads complete
#pragma unroll
    for (int it = 0; it < 4; ++it) {        // stage K chunk (coalesced)
      const int idx = it * 512 + tid;       // 0..2047 = 128 keys x 16 f4-slots
      const int i = idx >> 4, c4 = idx & 15;
      *(float4*)&Kst[i * 68 + c4 * 4] =
          *(const float4*)&qkvf[(base + c0 + i) * 3072 + 1024 + h * 64 + c4 * 4];
    }
    __syncthreads();

    for (int hf = 0; hf < 2; ++hf) {
      const int hs = c0 + hf * 64;
      if (hs > lastkey) break;              // block-uniform

      // K into regs: lane = key (hs + lane)
      float4 kq[16];
#pragma unroll
      for (int c4 = 0; c4 < 16; ++c4)
        kq[c4] = *(const float4*)&Kst[(hf * 64 + lane) * 68 + c4 * 4];
      // V into regs: lane = d, 64 coalesced global loads
      float vv[64];
#pragma unroll
      for (int j = 0; j < 64; ++j)
        vv[j] = qkvf[(base + hs + j) * 3072 + 2048 + h * 64 + lane];
      const int am = amask[b * SEQ + hs + lane];

#pragma unroll
      for (int k = 0; k < 8; ++k) {
        const int l = row0 + k * 8 + w;
        // scores: dot(q_row, K[key=lane])
        float4 sv = {0.f, 0.f, 0.f, 0.f};
#pragma unroll
        for (int c4 = 0; c4 < 16; ++c4) {
          const float4 qv = *(const float4*)&q_lds[w][k][c4 * 4];
          sv.x += kq[c4].x * qv.x; sv.y += kq[c4].y * qv.y;
          sv.z += kq[c4].z * qv.z; sv.w += kq[c4].w * qv.w;
        }
        float s = (sv.x + sv.y) + (sv.z + sv.w);
        const bool valid = (hs + lane <= l) && (am != 0);
        s = valid ? 30.f * tanhf(s * 0.125f) : -1e9f;

        float cmx = s;
#pragma unroll
        for (int o = 32; o; o >>= 1) cmx = fmaxf(cmx, __shfl_xor(cmx, o));
        const float nm = fmaxf(m_s[k], cmx);
        const float pp = __expf(s - nm);
        p_lds[w][lane] = pp;
        float cs = pp;
#pragma unroll
        for (int o = 32; o; o >>= 1) cs += __shfl_xor(cs, o);
        const float rs = __expf(m_s[k] - nm);
        m_s[k] = nm;
        sum_s[k] = sum_s[k] * rs + cs;
        __asm__ volatile("s_waitcnt lgkmcnt(0)" ::: "memory");

        // PV: lane = d, p broadcast
        float a0 = 0.f, a1 = 0.f, a2 = 0.f, a3 = 0.f;
#pragma unroll
        for (int i4 = 0; i4 < 16; ++i4) {
          const float4 p4 = *(const float4*)&p_lds[w][i4 * 4];
          a0 += p4.x * vv[i4 * 4 + 0];
          a1 += p4.y * vv[i4 * 4 + 1];
          a2 += p4.z * vv[i4 * 4 + 2];
          a3 += p4.w * vv[i4 * 4 + 3];
        }
        acc_s[k] = acc_s[k] * rs + ((a0 + a1) + (a2 + a3));
      }
    }
  }

#pragma unroll
  for (int k = 0; k < 8; ++k) {
    const int l = row0 + k * 8 + w;
    const float o = acc_s[k] / sum_s[k];
    unsigned short hh, ll;
    split2(o, hh, ll);
    out2[(base + l) * 2048 + h * 64 + lane] = hh;
    out2[(base + l) * 2048 + 1024 + h * 64 + lane] = ll;
  }
}

extern "C" void kernel_launch(void* const* d_in, const int* in_sizes, int n_in,
                              void* d_out, int out_size, void* d_ws, size_t ws_size,
                              hipStream_t stream) {
  const int*   ids       = (const int*)d_in[0];
  const int*   amask     = (const int*)d_in[1];
  const float* W_vocab   = (const float*)d_in[2];
  const float* W_devocab = (const float*)d_in[3];
  const float* WQ        = (const float*)d_in[4];
  const float* WK        = (const float*)d_in[5];
  const float* WV        = (const float*)d_in[6];
  const float* W_O       = (const float*)d_in[7];
  const float* gamma1    = (const float*)d_in[8];
  const float* beta1     = (const float*)d_in[9];
  const float* gamma2    = (const float*)d_in[10];
  const float* beta2     = (const float*)d_in[11];
  const float* W_up      = (const float*)d_in[12];
  const float* b_up      = (const float*)d_in[13];
  const float* W_down    = (const float*)d_in[14];
  const float* b_down    = (const float*)d_in[15];
  const float* gamma_f   = (const float*)d_in[16];
  const float* beta_f    = (const float*)d_in[17];

  char* p = (char*)d_ws;
  auto alloc = [&](size_t bytes) { char* r = p; p += (bytes + 255) & ~(size_t)255; return r; };

  unsigned short* WQKV2 = (unsigned short*)alloc((size_t)NLAYERS * 3072 * 2048 * 2);
  unsigned short* WO2   = (unsigned short*)alloc((size_t)NLAYERS * 1024 * 2048 * 2);
  unsigned short* WUp2  = (unsigned short*)alloc((size_t)NLAYERS * 4096 * 2048 * 2);
  unsigned short* WDn2  = (unsigned short*)alloc((size_t)NLAYERS * 1024 * 8192 * 2);
  unsigned short* WDev1 = (unsigned short*)alloc((size_t)VOCAB * 1024 * 2);
  float* x    = (float*)alloc((size_t)NTOK * 1024 * 4);
  float* z1   = (float*)alloc((size_t)NTOK * 1024 * 4);
  unsigned short* u2    = (unsigned short*)alloc((size_t)NTOK * 2048 * 2);   // also v1 / xf
  float* qkvf = (float*)alloc((size_t)NTOK * 3072 * 4);
  unsigned short* attn2 = (unsigned short*)alloc((size_t)NTOK * 2048 * 2);
  unsigned short* h2    = (unsigned short*)alloc((size_t)NTOK * 8192 * 2);
  (void)ws_size; (void)in_sizes; (void)n_in; (void)out_size;

  // ---- weight prep (hi/lo split planes) ----
  cvt_qkv_split<<<2048, 256, 0, stream>>>(WQ, WK, WV, WQKV2);
  cvt_split<<<2048, 256, 0, stream>>>(W_O, WO2, (long)NLAYERS * 1024, 1024);
  transpose_cvt_split<<<dim3(4096 / 32, 1024 / 32, NLAYERS), 256, 0, stream>>>(W_up, WUp2, 1024, 4096);
  transpose_cvt_split<<<dim3(1024 / 32, 4096 / 32, NLAYERS), 256, 0, stream>>>(W_down, WDn2, 4096, 1024);
  transpose_cvt<<<dim3(VOCAB / 32, 1024 / 32, 1), 256, 0, stream>>>(W_devocab, WDev1, 1024, VOCAB);

  // ---- embedding ----
  embed_kernel<<<NTOK, 256, 0, stream>>>(ids, W_vocab, x);

  // ---- layers ----
  for (int l = 0; l < NLAYERS; ++l) {
    layernorm_split<<<NTOK, 256, 0, stream>>>(x, gamma1 + l * 1024, beta1 + l * 1024, u2);
    // fused QKV (split-3, f32 out): [4096,3072]
    gemm_bt<0, 3><<<dim3(3072 / 128, NTOK / 128), 256, 0, stream>>>(
        u2, WQKV2 + (size_t)l * 3072 * 2048, qkvf, nullptr, nullptr, nullptr,
        NTOK, 3072, 1024);
    attn_kernel<<<BATCH * NHEADS * 8, 512, 0, stream>>>(qkvf, amask, attn2);
    // z1 = x + attn @ W_O^T
    gemm_bt<2, 3><<<dim3(1024 / 128, NTOK / 128), 256, 0, stream>>>(
        attn2, WO2 + (size_t)l * 1024 * 2048, z1, nullptr, nullptr, x,
        NTOK, 1024, 1024);
    layernorm_split<<<NTOK, 256, 0, stream>>>(z1, gamma2 + l * 1024, beta2 + l * 1024, u2);
    // h = gelu(v1 @ W_up + b_up), hi/lo out
    gemm_bt<3, 3><<<dim3(4096 / 128, NTOK / 128), 256, 0, stream>>>(
        u2, WUp2 + (size_t)l * 4096 * 2048, nullptr, h2, b_up + l * 4096, nullptr,
        NTOK, 4096, 1024);
    // x = z1 + h @ W_down + b_down
    gemm_bt<4, 3><<<dim3(1024 / 128, NTOK / 128), 256, 0, stream>>>(
        h2, WDn2 + (size_t)l * 1024 * 8192, x, nullptr, b_down + l * 1024, z1,
        NTOK, 1024, 4096);
  }

  // ---- final LN + devocab (split-2: x hi/lo, W hi only) ----
  layernorm_split<<<NTOK, 256, 0, stream>>>(x, gamma_f, beta_f, u2);
  gemm_bt<0, 2><<<dim3(VOCAB / 128, NTOK / 128), 256, 0, stream>>>(
      u2, WDev1, (float*)d_out, nullptr, nullptr, nullptr,
      NTOK, VOCAB, 1024);
}

// Round 8
// 20188.545 us; speedup vs baseline: 1.8582x; 1.8582x over previous
//
#include <hip/hip_runtime.h>
#include <math.h>

#define D_MODEL 1024
#define NHEADS 16
#define DHEAD 64
#define NLAYERS 12
#define VOCAB 32000
#define BATCH 8
#define SEQ 512
#define NTOK (BATCH*SEQ)   // 4096

using short8 = __attribute__((ext_vector_type(8))) short;
using fx4    = __attribute__((ext_vector_type(4))) float;

#define GLL16(g, l) __builtin_amdgcn_global_load_lds( \
    (const __attribute__((address_space(1))) unsigned int*)(g), \
    (__attribute__((address_space(3))) unsigned int*)(l), 16, 0, 0)

__device__ __forceinline__ unsigned short f2bf(float f) {
  union { float f; unsigned u; } v; v.f = f;
  unsigned r = v.u + 0x7FFFu + ((v.u >> 16) & 1u);
  return (unsigned short)(r >> 16);
}
__device__ __forceinline__ float bf2f(unsigned short u) {
  union { unsigned u; float f; } v; v.u = ((unsigned)u) << 16;
  return v.f;
}
__device__ __forceinline__ void split2(float x, unsigned short& h, unsigned short& l) {
  h = f2bf(x);
  l = f2bf(x - bf2f(h));
}
__device__ __forceinline__ float gelu_exact(float x) {
  return 0.5f * x * (1.f + erff(x * 0.70710678118654752f));
}

// ---------------- weight conversion (hi/lo split planes) ----------------

__global__ __launch_bounds__(256) void cvt_qkv_split(const float* __restrict__ WQ,
    const float* __restrict__ WK, const float* __restrict__ WV,
    unsigned short* __restrict__ out)
{
  const long total = 12L * 3072 * 256;     // float4 units
  const long stride = (long)gridDim.x * blockDim.x;
  for (long t = (long)blockIdx.x * blockDim.x + threadIdx.x; t < total; t += stride) {
    const long layer = t / (3072L * 256);
    const long rem = t - layer * (3072L * 256);
    const int n = (int)(rem >> 8);
    const int k4 = (int)(rem & 255);
    const float* src;
    if (n < 1024)       src = WQ + ((size_t)layer * 1024 + n) * 1024;
    else if (n < 2048)  src = WK + ((size_t)layer * 1024 + (n - 1024)) * 1024;
    else                src = WV + ((size_t)layer * 1024 + (n - 2048)) * 1024;
    const float4 v = *(const float4*)(src + k4 * 4);
    ushort4 h, l; unsigned short a, b;
    split2(v.x, a, b); h.x = a; l.x = b;
    split2(v.y, a, b); h.y = a; l.y = b;
    split2(v.z, a, b); h.z = a; l.z = b;
    split2(v.w, a, b); h.w = a; l.w = b;
    unsigned short* dst = out + ((size_t)layer * 3072 + n) * 2048 + k4 * 4;
    *(ushort4*)dst = h;
    *(ushort4*)(dst + 1024) = l;
  }
}

__global__ __launch_bounds__(256) void cvt_split(const float* __restrict__ in,
    unsigned short* __restrict__ out, long rows, int K)
{
  const int K4 = K >> 2;
  const long total = rows * K4;
  const long stride = (long)gridDim.x * blockDim.x;
  for (long t = (long)blockIdx.x * blockDim.x + threadIdx.x; t < total; t += stride) {
    const long r = t / K4;
    const int k4 = (int)(t - r * K4);
    const float4 v = *(const float4*)(in + r * K + k4 * 4);
    ushort4 h, l; unsigned short a, b;
    split2(v.x, a, b); h.x = a; l.x = b;
    split2(v.y, a, b); h.y = a; l.y = b;
    split2(v.z, a, b); h.z = a; l.z = b;
    split2(v.w, a, b); h.w = a; l.w = b;
    unsigned short* dst = out + r * 2 * K + k4 * 4;
    *(ushort4*)dst = h;
    *(ushort4*)(dst + K) = l;
  }
}

__global__ __launch_bounds__(256) void transpose_cvt_split(const float* __restrict__ in,
    unsigned short* __restrict__ out, int R, int C)
{
  __shared__ float tile[32][33];
  in  += (size_t)blockIdx.z * R * C;
  out += (size_t)blockIdx.z * 2 * R * C;
  const int r0 = blockIdx.y * 32, c0 = blockIdx.x * 32;
  const int tr = threadIdx.x >> 5, tc = threadIdx.x & 31;
#pragma unroll
  for (int i = 0; i < 4; ++i)
    tile[tr + i * 8][tc] = in[(size_t)(r0 + tr + i * 8) * C + c0 + tc];
  __syncthreads();
#pragma unroll
  for (int i = 0; i < 4; ++i) {
    unsigned short h, l;
    split2(tile[tc][tr + i * 8], h, l);
    const size_t o = (size_t)(c0 + tr + i * 8) * 2 * R + r0 + tc;
    out[o] = h;
    out[o + R] = l;
  }
}

__global__ __launch_bounds__(256) void transpose_cvt(const float* __restrict__ in,
    unsigned short* __restrict__ out, int R, int C)
{
  __shared__ float tile[32][33];
  const int r0 = blockIdx.y * 32, c0 = blockIdx.x * 32;
  const int tr = threadIdx.x >> 5, tc = threadIdx.x & 31;
#pragma unroll
  for (int i = 0; i < 4; ++i)
    tile[tr + i * 8][tc] = in[(size_t)(r0 + tr + i * 8) * C + c0 + tc];
  __syncthreads();
#pragma unroll
  for (int i = 0; i < 4; ++i)
    out[(size_t)(c0 + tr + i * 8) * R + r0 + tc] = f2bf(tile[tc][tr + i * 8]);
}

// ---------------- embedding + positional ----------------

__global__ __launch_bounds__(256) void embed_kernel(const int* __restrict__ ids,
    const float* __restrict__ Wv, float* __restrict__ x)
{
  const int t = blockIdx.x;
  const int id = ids[t];
  const int l = t & (SEQ - 1);
  const float pos = (float)l;
  const int d0 = threadIdx.x * 4;
  const float i0 = (float)(d0 >> 1);
  const float f0 = expf(-0.017988946039016f * i0);
  const float f1 = expf(-0.017988946039016f * (i0 + 1.f));
  const float a0 = pos * f0, a1 = pos * f1;
  float4 v;
  v.x = Wv[(size_t)(d0 + 0) * VOCAB + id] + sinf(a0);
  v.y = Wv[(size_t)(d0 + 1) * VOCAB + id] + cosf(a0);
  v.z = Wv[(size_t)(d0 + 2) * VOCAB + id] + sinf(a1);
  v.w = Wv[(size_t)(d0 + 3) * VOCAB + id] + cosf(a1);
  ((float4*)(x + (size_t)t * 1024))[threadIdx.x] = v;
}

// ---------------- layernorm (f32 in -> hi/lo bf16 planes out, stride 2048) ----------------

__global__ __launch_bounds__(256) void layernorm_split(const float* __restrict__ x,
    const float* __restrict__ g, const float* __restrict__ be,
    unsigned short* __restrict__ out)
{
  const int row = blockIdx.x;
  const float4 v = ((const float4*)(x + (size_t)row * 1024))[threadIdx.x];
  float s = v.x + v.y + v.z + v.w;
  float q = v.x * v.x + v.y * v.y + v.z * v.z + v.w * v.w;
#pragma unroll
  for (int o = 32; o; o >>= 1) { s += __shfl_xor(s, o); q += __shfl_xor(q, o); }
  __shared__ float ss[4], qq[4];
  const int w = threadIdx.x >> 6;
  if ((threadIdx.x & 63) == 0) { ss[w] = s; qq[w] = q; }
  __syncthreads();
  s = ss[0] + ss[1] + ss[2] + ss[3];
  q = qq[0] + qq[1] + qq[2] + qq[3];
  const float mean = s * (1.f / 1024.f);
  const float var = q * (1.f / 1024.f) - mean * mean;
  const float rstd = rsqrtf(var + 1e-5f);
  const float4 gv = ((const float4*)g)[threadIdx.x];
  const float4 bv = ((const float4*)be)[threadIdx.x];
  float4 y;
  y.x = (v.x - mean) * rstd * gv.x + bv.x;
  y.y = (v.y - mean) * rstd * gv.y + bv.y;
  y.z = (v.z - mean) * rstd * gv.z + bv.z;
  y.w = (v.w - mean) * rstd * gv.w + bv.w;
  ushort4 h4, l4; unsigned short a, b;
  split2(y.x, a, b); h4.x = a; l4.x = b;
  split2(y.y, a, b); h4.y = a; l4.y = b;
  split2(y.z, a, b); h4.z = a; l4.z = b;
  split2(y.w, a, b); h4.w = a; l4.w = b;
  unsigned short* dst = out + (size_t)row * 2048 + threadIdx.x * 4;
  *(ushort4*)dst = h4;
  *(ushort4*)(dst + 1024) = l4;
}

// ---------------- split GEMM: C[M,N] = A[M,K] * B[N,K]^T, near-f32 precision ----------------
// global_load_lds width-16 staging (m97 pattern). No XCD swizzle (operands L2/L3-fit).

template<int EPI, int SPLIT>
__global__ __launch_bounds__(256) void gemm_bt(
    const unsigned short* __restrict__ A, const unsigned short* __restrict__ B,
    float* __restrict__ Cf, unsigned short* __restrict__ Cb,
    const float* __restrict__ bias, const float* __restrict__ res,
    int M, int N, int K)
{
  __shared__ __align__(16) unsigned short As[128 * 64];
  __shared__ __align__(16) unsigned short Bs[128 * 64];
  const int tid = threadIdx.x;
  const int lane = tid & 63, w = tid >> 6;
  const int wr = w >> 1, wc = w & 1;
  const int brow = blockIdx.y * 128, bcol = blockIdx.x * 128;

  const int SA = 2 * K;                         // A always hi/lo
  const int SB = (SPLIT == 3) ? 2 * K : K;
  const int KEFF = SPLIT * K;
  fx4 acc[4][4];
  const fx4 zero = {0.f, 0.f, 0.f, 0.f};
#pragma unroll
  for (int i = 0; i < 4; ++i)
#pragma unroll
    for (int j = 0; j < 4; ++j) acc[i][j] = zero;

  const unsigned short* Ab = A + (size_t)brow * SA;
  const unsigned short* Bb = B + (size_t)bcol * SB;

  for (int k0 = 0; k0 < KEFF; k0 += 64) {
    int ka, kb;
    if (SPLIT == 3) {
      ka = (k0 < 2 * K) ? k0 : k0 - 2 * K;      // hi | lo | hi
      kb = (k0 < K) ? k0 : k0 - K;              // hi | hi | lo
    } else {
      ka = k0;                                  // hi | lo
      kb = (k0 < K) ? k0 : k0 - K;              // hi | hi
    }
    const unsigned short* Aseg = Ab + ka;
    const unsigned short* Bseg = Bb + kb;
#pragma unroll
    for (int it = 0; it < 4; ++it) {
      const int idx = it * 256 + tid;          // 0..1023
      const int r = idx >> 3, c = (idx & 7) * 8;
      GLL16(&Aseg[(size_t)r * SA + c], &As[idx * 8]);
      GLL16(&Bseg[(size_t)r * SB + c], &Bs[idx * 8]);
    }
    __syncthreads();   // drains vmcnt (global_load_lds) before ds_read
#pragma unroll
    for (int kk = 0; kk < 2; ++kk) {
      short8 af[4], bfv[4];
      const int kof = kk * 32 + (lane >> 4) * 8;
#pragma unroll
      for (int f = 0; f < 4; ++f)
        af[f] = *(const short8*)&As[(wr * 64 + f * 16 + (lane & 15)) * 64 + kof];
#pragma unroll
      for (int f = 0; f < 4; ++f)
        bfv[f] = *(const short8*)&Bs[(wc * 64 + f * 16 + (lane & 15)) * 64 + kof];
#pragma unroll
      for (int i = 0; i < 4; ++i)
#pragma unroll
        for (int j = 0; j < 4; ++j)
          acc[i][j] = __builtin_amdgcn_mfma_f32_16x16x32_bf16(af[i], bfv[j], acc[i][j], 0, 0, 0);
    }
    __syncthreads();
  }

  // C/D layout: col = lane&15, row = (lane>>4)*4 + reg
  const int r0 = brow + wr * 64 + (lane >> 4) * 4;
  const int c0 = bcol + wc * 64 + (lane & 15);
#pragma unroll
  for (int i = 0; i < 4; ++i) {
#pragma unroll
    for (int j = 0; j < 4; ++j) {
      const int cc = c0 + j * 16;
#pragma unroll
      for (int qi = 0; qi < 4; ++qi) {
        const int rr = r0 + i * 16 + qi;
        const size_t off = (size_t)rr * N + cc;
        const float val = acc[i][j][qi];
        if (EPI == 0) {
          Cf[off] = val;
        } else if (EPI == 2) {
          Cf[off] = res[off] + val;
        } else if (EPI == 3) {
          unsigned short hh, ll;
          split2(gelu_exact(val + bias[cc]), hh, ll);
          Cb[(size_t)rr * (2 * N) + cc] = hh;
          Cb[(size_t)rr * (2 * N) + N + cc] = ll;
        } else {
          Cf[off] = res[off] + val + bias[cc];
        }
      }
    }
  }
}

// ---------------- attention v3: flash online softmax, phase-split register use ----------------
// grid.x = B*H*16 ; block = 256 (4 waves). Block: (b, h, 32-row tile); wave owns 8 rows.
// Per 64-key half:
//   Phase A (lane=key): K in regs (kq[16] f4), q broadcast from LDS -> raw tanh scores to p_lds.
//   Phase B (lane=d):   V in regs (vv[64] scalar), shuffle softmax + PV, p broadcast from LDS.
// kq and vv are never simultaneously live -> ~110-130 VGPR, no spill, 3 waves/SIMD.
// qkvf: [NTOK][3072] f32 (q|k|v). out2: [NTOK][2048] bf16 hi|lo planes.

__global__ __launch_bounds__(256) void attn_kernel(
    const float* __restrict__ qkvf,
    const int* __restrict__ amask,
    unsigned short* __restrict__ out2)
{
  const int bid = blockIdx.x;
  const int rt = bid & 15;
  const int h  = (bid >> 4) & 15;
  const int b  = bid >> 8;
  const int row0 = rt * 32;

  __shared__ __align__(16) float Kst[128 * 68];     // [key][d], stride 68 dwords
  __shared__ __align__(16) float q_lds[4][8][64];   // [wave][rowk][d]
  __shared__ __align__(16) float p_lds[4][8][64];   // [wave][rowk][key]

  const int tid = threadIdx.x, lane = tid & 63, w = tid >> 6;
  const size_t base = (size_t)b * SEQ;

  // hoist q rows for this wave into LDS
#pragma unroll
  for (int k = 0; k < 8; ++k) {
    const int l = row0 + w * 8 + k;
    q_lds[w][k][lane] = qkvf[(base + l) * 3072 + h * 64 + lane];
  }

  float m_s[8], sum_s[8], acc_s[8];
#pragma unroll
  for (int k = 0; k < 8; ++k) { m_s[k] = -1e9f; sum_s[k] = 0.f; acc_s[k] = 0.f; }

  const int lastkey = row0 + 31;
  const int nch = (row0 + 32 + 127) >> 7;       // 128-key chunks covering 0..lastkey
  for (int ch = 0; ch < nch; ++ch) {
    const int c0 = ch << 7;
    __syncthreads();                            // prev chunk fully consumed
#pragma unroll
    for (int it = 0; it < 8; ++it) {            // stage K chunk (coalesced f4)
      const int idx = it * 256 + tid;           // 0..2047 = 128 keys x 16 f4-slots
      const int i = idx >> 4, c4 = idx & 15;
      *(float4*)&Kst[i * 68 + c4 * 4] =
          *(const float4*)&qkvf[(base + c0 + i) * 3072 + 1024 + h * 64 + c4 * 4];
    }
    __syncthreads();

    for (int hf = 0; hf < 2; ++hf) {
      const int hs = c0 + (hf << 6);
      if (hs > lastkey) break;                  // block-uniform
      const int key = hs + lane;

      // ---- Phase A: scores (lane = key) ----
      {
        float4 kq[16];
#pragma unroll
        for (int c4 = 0; c4 < 16; ++c4)
          kq[c4] = *(const float4*)&Kst[((hf << 6) + lane) * 68 + c4 * 4];
        const int am = amask[b * SEQ + key];
#pragma unroll
        for (int k = 0; k < 8; ++k) {
          const int l = row0 + w * 8 + k;
          float4 sv = {0.f, 0.f, 0.f, 0.f};
#pragma unroll
          for (int c4 = 0; c4 < 16; ++c4) {
            const float4 qv = *(const float4*)&q_lds[w][k][c4 * 4];
            sv.x += kq[c4].x * qv.x; sv.y += kq[c4].y * qv.y;
            sv.z += kq[c4].z * qv.z; sv.w += kq[c4].w * qv.w;
          }
          const float s = (sv.x + sv.y) + (sv.z + sv.w);
          const bool valid = (key <= l) && (am != 0);
          p_lds[w][k][lane] = valid ? 30.f * tanhf(s * 0.125f) : -1e9f;
        }
      }
      __asm__ volatile("s_waitcnt lgkmcnt(0)" ::: "memory");

      // ---- Phase B: softmax + PV (lane = d) ----
      {
        float vv[64];
#pragma unroll
        for (int j = 0; j < 64; ++j)
          vv[j] = qkvf[(base + hs + j) * 3072 + 2048 + h * 64 + lane];

#pragma unroll
        for (int k = 0; k < 8; ++k) {
          const float S = p_lds[w][k][lane];
          float cmx = S;
#pragma unroll
          for (int o = 32; o; o >>= 1) cmx = fmaxf(cmx, __shfl_xor(cmx, o));
          const float nm = fmaxf(m_s[k], cmx);
          const float pp = __expf(S - nm);
          p_lds[w][k][lane] = pp;
          float cs = pp;
#pragma unroll
          for (int o = 32; o; o >>= 1) cs += __shfl_xor(cs, o);
          const float rs = __expf(m_s[k] - nm);
          m_s[k] = nm;
          sum_s[k] = sum_s[k] * rs + cs;
          __asm__ volatile("s_waitcnt lgkmcnt(0)" ::: "memory");

          float a0 = 0.f, a1 = 0.f, a2 = 0.f, a3 = 0.f;
#pragma unroll
          for (int i4 = 0; i4 < 16; ++i4) {
            const float4 p4 = *(const float4*)&p_lds[w][k][i4 * 4];
            a0 += p4.x * vv[i4 * 4 + 0];
            a1 += p4.y * vv[i4 * 4 + 1];
            a2 += p4.z * vv[i4 * 4 + 2];
            a3 += p4.w * vv[i4 * 4 + 3];
          }
          acc_s[k] = acc_s[k] * rs + ((a0 + a1) + (a2 + a3));
        }
      }
    }
  }

#pragma unroll
  for (int k = 0; k < 8; ++k) {
    const int l = row0 + w * 8 + k;
    const float o = acc_s[k] / sum_s[k];
    unsigned short hh, ll;
    split2(o, hh, ll);
    out2[(base + l) * 2048 + h * 64 + lane] = hh;
    out2[(base + l) * 2048 + 1024 + h * 64 + lane] = ll;
  }
}

extern "C" void kernel_launch(void* const* d_in, const int* in_sizes, int n_in,
                              void* d_out, int out_size, void* d_ws, size_t ws_size,
                              hipStream_t stream) {
  const int*   ids       = (const int*)d_in[0];
  const int*   amask     = (const int*)d_in[1];
  const float* W_vocab   = (const float*)d_in[2];
  const float* W_devocab = (const float*)d_in[3];
  const float* WQ        = (const float*)d_in[4];
  const float* WK        = (const float*)d_in[5];
  const float* WV        = (const float*)d_in[6];
  const float* W_O       = (const float*)d_in[7];
  const float* gamma1    = (const float*)d_in[8];
  const float* beta1     = (const float*)d_in[9];
  const float* gamma2    = (const float*)d_in[10];
  const float* beta2     = (const float*)d_in[11];
  const float* W_up      = (const float*)d_in[12];
  const float* b_up      = (const float*)d_in[13];
  const float* W_down    = (const float*)d_in[14];
  const float* b_down    = (const float*)d_in[15];
  const float* gamma_f   = (const float*)d_in[16];
  const float* beta_f    = (const float*)d_in[17];

  char* p = (char*)d_ws;
  auto alloc = [&](size_t bytes) { char* r = p; p += (bytes + 255) & ~(size_t)255; return r; };

  unsigned short* WQKV2 = (unsigned short*)alloc((size_t)NLAYERS * 3072 * 2048 * 2);
  unsigned short* WO2   = (unsigned short*)alloc((size_t)NLAYERS * 1024 * 2048 * 2);
  unsigned short* WUp2  = (unsigned short*)alloc((size_t)NLAYERS * 4096 * 2048 * 2);
  unsigned short* WDn2  = (unsigned short*)alloc((size_t)NLAYERS * 1024 * 8192 * 2);
  unsigned short* WDev1 = (unsigned short*)alloc((size_t)VOCAB * 1024 * 2);
  float* x    = (float*)alloc((size_t)NTOK * 1024 * 4);
  float* z1   = (float*)alloc((size_t)NTOK * 1024 * 4);
  unsigned short* u2    = (unsigned short*)alloc((size_t)NTOK * 2048 * 2);   // also v1 / xf
  float* qkvf = (float*)alloc((size_t)NTOK * 3072 * 4);
  unsigned short* attn2 = (unsigned short*)alloc((size_t)NTOK * 2048 * 2);
  unsigned short* h2    = (unsigned short*)alloc((size_t)NTOK * 8192 * 2);
  (void)ws_size; (void)in_sizes; (void)n_in; (void)out_size;

  // ---- weight prep (hi/lo split planes) ----
  cvt_qkv_split<<<2048, 256, 0, stream>>>(WQ, WK, WV, WQKV2);
  cvt_split<<<2048, 256, 0, stream>>>(W_O, WO2, (long)NLAYERS * 1024, 1024);
  transpose_cvt_split<<<dim3(4096 / 32, 1024 / 32, NLAYERS), 256, 0, stream>>>(W_up, WUp2, 1024, 4096);
  transpose_cvt_split<<<dim3(1024 / 32, 4096 / 32, NLAYERS), 256, 0, stream>>>(W_down, WDn2, 4096, 1024);
  transpose_cvt<<<dim3(VOCAB / 32, 1024 / 32, 1), 256, 0, stream>>>(W_devocab, WDev1, 1024, VOCAB);

  // ---- embedding ----
  embed_kernel<<<NTOK, 256, 0, stream>>>(ids, W_vocab, x);

  // ---- layers ----
  for (int l = 0; l < NLAYERS; ++l) {
    layernorm_split<<<NTOK, 256, 0, stream>>>(x, gamma1 + l * 1024, beta1 + l * 1024, u2);
    // fused QKV (split-3, f32 out): [4096,3072]
    gemm_bt<0, 3><<<dim3(3072 / 128, NTOK / 128), 256, 0, stream>>>(
        u2, WQKV2 + (size_t)l * 3072 * 2048, qkvf, nullptr, nullptr, nullptr,
        NTOK, 3072, 1024);
    attn_kernel<<<BATCH * NHEADS * 16, 256, 0, stream>>>(qkvf, amask, attn2);
    // z1 = x + attn @ W_O^T
    gemm_bt<2, 3><<<dim3(1024 / 128, NTOK / 128), 256, 0, stream>>>(
        attn2, WO2 + (size_t)l * 1024 * 2048, z1, nullptr, nullptr, x,
        NTOK, 1024, 1024);
    layernorm_split<<<NTOK, 256, 0, stream>>>(z1, gamma2 + l * 1024, beta2 + l * 1024, u2);
    // h = gelu(v1 @ W_up + b_up), hi/lo out
    gemm_bt<3, 3><<<dim3(4096 / 128, NTOK / 128), 256, 0, stream>>>(
        u2, WUp2 + (size_t)l * 4096 * 2048, nullptr, h2, b_up + l * 4096, nullptr,
        NTOK, 4096, 1024);
    // x = z1 + h @ W_down + b_down
    gemm_bt<4, 3><<<dim3(1024 / 128, NTOK / 128), 256, 0, stream>>>(
        h2, WDn2 + (size_t)l * 1024 * 8192, x, nullptr, b_down + l * 1024, z1,
        NTOK, 1024, 4096);
  }

  // ---- final LN + devocab (split-2: x hi/lo, W hi only) ----
  layernorm_split<<<NTOK, 256, 0, stream>>>(x, gamma_f, beta_f, u2);
  gemm_bt<0, 2><<<dim3(VOCAB / 128, NTOK / 128), 256, 0, stream>>>(
      u2, WDev1, (float*)d_out, nullptr, nullptr, nullptr,
      NTOK, VOCAB, 1024);
}

// Round 9
// 17333.934 us; speedup vs baseline: 2.1642x; 1.1647x over previous
//
#include <hip/hip_runtime.h>
#include <math.h>

#define D_MODEL 1024
#define NHEADS 16
#define DHEAD 64
#define NLAYERS 12
#define VOCAB 32000
#define BATCH 8
#define SEQ 512
#define NTOK (BATCH*SEQ)   // 4096

using short8 = __attribute__((ext_vector_type(8))) short;
using fx4    = __attribute__((ext_vector_type(4))) float;

#define GLL16(g, l) __builtin_amdgcn_global_load_lds( \
    (const __attribute__((address_space(1))) unsigned int*)(g), \
    (__attribute__((address_space(3))) unsigned int*)(l), 16, 0, 0)

__device__ __forceinline__ unsigned short f2bf(float f) {
  union { float f; unsigned u; } v; v.f = f;
  unsigned r = v.u + 0x7FFFu + ((v.u >> 16) & 1u);
  return (unsigned short)(r >> 16);
}
__device__ __forceinline__ float bf2f(unsigned short u) {
  union { unsigned u; float f; } v; v.u = ((unsigned)u) << 16;
  return v.f;
}
__device__ __forceinline__ void split2(float x, unsigned short& h, unsigned short& l) {
  h = f2bf(x);
  l = f2bf(x - bf2f(h));
}
__device__ __forceinline__ float gelu_exact(float x) {
  return 0.5f * x * (1.f + erff(x * 0.70710678118654752f));
}

// ---------------- weight conversion (hi/lo split planes) ----------------

__global__ __launch_bounds__(256) void cvt_qkv_split(const float* __restrict__ WQ,
    const float* __restrict__ WK, const float* __restrict__ WV,
    unsigned short* __restrict__ out)
{
  const long total = 12L * 3072 * 256;     // float4 units
  const long stride = (long)gridDim.x * blockDim.x;
  for (long t = (long)blockIdx.x * blockDim.x + threadIdx.x; t < total; t += stride) {
    const long layer = t / (3072L * 256);
    const long rem = t - layer * (3072L * 256);
    const int n = (int)(rem >> 8);
    const int k4 = (int)(rem & 255);
    const float* src;
    if (n < 1024)       src = WQ + ((size_t)layer * 1024 + n) * 1024;
    else if (n < 2048)  src = WK + ((size_t)layer * 1024 + (n - 1024)) * 1024;
    else                src = WV + ((size_t)layer * 1024 + (n - 2048)) * 1024;
    const float4 v = *(const float4*)(src + k4 * 4);
    ushort4 h, l; unsigned short a, b;
    split2(v.x, a, b); h.x = a; l.x = b;
    split2(v.y, a, b); h.y = a; l.y = b;
    split2(v.z, a, b); h.z = a; l.z = b;
    split2(v.w, a, b); h.w = a; l.w = b;
    unsigned short* dst = out + ((size_t)layer * 3072 + n) * 2048 + k4 * 4;
    *(ushort4*)dst = h;
    *(ushort4*)(dst + 1024) = l;
  }
}

__global__ __launch_bounds__(256) void cvt_split(const float* __restrict__ in,
    unsigned short* __restrict__ out, long rows, int K)
{
  const int K4 = K >> 2;
  const long total = rows * K4;
  const long stride = (long)gridDim.x * blockDim.x;
  for (long t = (long)blockIdx.x * blockDim.x + threadIdx.x; t < total; t += stride) {
    const long r = t / K4;
    const int k4 = (int)(t - r * K4);
    const float4 v = *(const float4*)(in + r * K + k4 * 4);
    ushort4 h, l; unsigned short a, b;
    split2(v.x, a, b); h.x = a; l.x = b;
    split2(v.y, a, b); h.y = a; l.y = b;
    split2(v.z, a, b); h.z = a; l.z = b;
    split2(v.w, a, b); h.w = a; l.w = b;
    unsigned short* dst = out + r * 2 * K + k4 * 4;
    *(ushort4*)dst = h;
    *(ushort4*)(dst + K) = l;
  }
}

__global__ __launch_bounds__(256) void transpose_cvt_split(const float* __restrict__ in,
    unsigned short* __restrict__ out, int R, int C)
{
  __shared__ float tile[32][33];
  in  += (size_t)blockIdx.z * R * C;
  out += (size_t)blockIdx.z * 2 * R * C;
  const int r0 = blockIdx.y * 32, c0 = blockIdx.x * 32;
  const int tr = threadIdx.x >> 5, tc = threadIdx.x & 31;
#pragma unroll
  for (int i = 0; i < 4; ++i)
    tile[tr + i * 8][tc] = in[(size_t)(r0 + tr + i * 8) * C + c0 + tc];
  __syncthreads();
#pragma unroll
  for (int i = 0; i < 4; ++i) {
    unsigned short h, l;
    split2(tile[tc][tr + i * 8], h, l);
    const size_t o = (size_t)(c0 + tr + i * 8) * 2 * R + r0 + tc;
    out[o] = h;
    out[o + R] = l;
  }
}

__global__ __launch_bounds__(256) void transpose_cvt(const float* __restrict__ in,
    unsigned short* __restrict__ out, int R, int C)
{
  __shared__ float tile[32][33];
  const int r0 = blockIdx.y * 32, c0 = blockIdx.x * 32;
  const int tr = threadIdx.x >> 5, tc = threadIdx.x & 31;
#pragma unroll
  for (int i = 0; i < 4; ++i)
    tile[tr + i * 8][tc] = in[(size_t)(r0 + tr + i * 8) * C + c0 + tc];
  __syncthreads();
#pragma unroll
  for (int i = 0; i < 4; ++i)
    out[(size_t)(c0 + tr + i * 8) * R + r0 + tc] = f2bf(tile[tc][tr + i * 8]);
}

// ---------------- embedding + positional ----------------

__global__ __launch_bounds__(256) void embed_kernel(const int* __restrict__ ids,
    const float* __restrict__ Wv, float* __restrict__ x)
{
  const int t = blockIdx.x;
  const int id = ids[t];
  const int l = t & (SEQ - 1);
  const float pos = (float)l;
  const int d0 = threadIdx.x * 4;
  const float i0 = (float)(d0 >> 1);
  const float f0 = expf(-0.017988946039016f * i0);
  const float f1 = expf(-0.017988946039016f * (i0 + 1.f));
  const float a0 = pos * f0, a1 = pos * f1;
  float4 v;
  v.x = Wv[(size_t)(d0 + 0) * VOCAB + id] + sinf(a0);
  v.y = Wv[(size_t)(d0 + 1) * VOCAB + id] + cosf(a0);
  v.z = Wv[(size_t)(d0 + 2) * VOCAB + id] + sinf(a1);
  v.w = Wv[(size_t)(d0 + 3) * VOCAB + id] + cosf(a1);
  ((float4*)(x + (size_t)t * 1024))[threadIdx.x] = v;
}

// ---------------- layernorm (f32 in -> hi/lo bf16 planes out, stride 2048) ----------------

__global__ __launch_bounds__(256) void layernorm_split(const float* __restrict__ x,
    const float* __restrict__ g, const float* __restrict__ be,
    unsigned short* __restrict__ out)
{
  const int row = blockIdx.x;
  const float4 v = ((const float4*)(x + (size_t)row * 1024))[threadIdx.x];
  float s = v.x + v.y + v.z + v.w;
  float q = v.x * v.x + v.y * v.y + v.z * v.z + v.w * v.w;
#pragma unroll
  for (int o = 32; o; o >>= 1) { s += __shfl_xor(s, o); q += __shfl_xor(q, o); }
  __shared__ float ss[4], qq[4];
  const int w = threadIdx.x >> 6;
  if ((threadIdx.x & 63) == 0) { ss[w] = s; qq[w] = q; }
  __syncthreads();
  s = ss[0] + ss[1] + ss[2] + ss[3];
  q = qq[0] + qq[1] + qq[2] + qq[3];
  const float mean = s * (1.f / 1024.f);
  const float var = q * (1.f / 1024.f) - mean * mean;
  const float rstd = rsqrtf(var + 1e-5f);
  const float4 gv = ((const float4*)g)[threadIdx.x];
  const float4 bv = ((const float4*)be)[threadIdx.x];
  float4 y;
  y.x = (v.x - mean) * rstd * gv.x + bv.x;
  y.y = (v.y - mean) * rstd * gv.y + bv.y;
  y.z = (v.z - mean) * rstd * gv.z + bv.z;
  y.w = (v.w - mean) * rstd * gv.w + bv.w;
  ushort4 h4, l4; unsigned short a, b;
  split2(y.x, a, b); h4.x = a; l4.x = b;
  split2(y.y, a, b); h4.y = a; l4.y = b;
  split2(y.z, a, b); h4.z = a; l4.z = b;
  split2(y.w, a, b); h4.w = a; l4.w = b;
  unsigned short* dst = out + (size_t)row * 2048 + threadIdx.x * 4;
  *(ushort4*)dst = h4;
  *(ushort4*)(dst + 1024) = l4;
}

// ---------------- split GEMM: C[M,N] = A[M,K] * B[N,K]^T, near-f32 precision ----------------
// global_load_lds width-16 staging (m97 pattern). No XCD swizzle (operands L2/L3-fit).

template<int EPI, int SPLIT>
__global__ __launch_bounds__(256) void gemm_bt(
    const unsigned short* __restrict__ A, const unsigned short* __restrict__ B,
    float* __restrict__ Cf, unsigned short* __restrict__ Cb,
    const float* __restrict__ bias, const float* __restrict__ res,
    int M, int N, int K)
{
  __shared__ __align__(16) unsigned short As[128 * 64];
  __shared__ __align__(16) unsigned short Bs[128 * 64];
  const int tid = threadIdx.x;
  const int lane = tid & 63, w = tid >> 6;
  const int wr = w >> 1, wc = w & 1;
  const int brow = blockIdx.y * 128, bcol = blockIdx.x * 128;

  const int SA = 2 * K;                         // A always hi/lo
  const int SB = (SPLIT == 3) ? 2 * K : K;
  const int KEFF = SPLIT * K;
  fx4 acc[4][4];
  const fx4 zero = {0.f, 0.f, 0.f, 0.f};
#pragma unroll
  for (int i = 0; i < 4; ++i)
#pragma unroll
    for (int j = 0; j < 4; ++j) acc[i][j] = zero;

  const unsigned short* Ab = A + (size_t)brow * SA;
  const unsigned short* Bb = B + (size_t)bcol * SB;

  for (int k0 = 0; k0 < KEFF; k0 += 64) {
    int ka, kb;
    if (SPLIT == 3) {
      ka = (k0 < 2 * K) ? k0 : k0 - 2 * K;      // hi | lo | hi
      kb = (k0 < K) ? k0 : k0 - K;              // hi | hi | lo
    } else {
      ka = k0;                                  // hi | lo
      kb = (k0 < K) ? k0 : k0 - K;              // hi | hi
    }
    const unsigned short* Aseg = Ab + ka;
    const unsigned short* Bseg = Bb + kb;
#pragma unroll
    for (int it = 0; it < 4; ++it) {
      const int idx = it * 256 + tid;          // 0..1023
      const int r = idx >> 3, c = (idx & 7) * 8;
      GLL16(&Aseg[(size_t)r * SA + c], &As[idx * 8]);
      GLL16(&Bseg[(size_t)r * SB + c], &Bs[idx * 8]);
    }
    __syncthreads();   // drains vmcnt (global_load_lds) before ds_read
#pragma unroll
    for (int kk = 0; kk < 2; ++kk) {
      short8 af[4], bfv[4];
      const int kof = kk * 32 + (lane >> 4) * 8;
#pragma unroll
      for (int f = 0; f < 4; ++f)
        af[f] = *(const short8*)&As[(wr * 64 + f * 16 + (lane & 15)) * 64 + kof];
#pragma unroll
      for (int f = 0; f < 4; ++f)
        bfv[f] = *(const short8*)&Bs[(wc * 64 + f * 16 + (lane & 15)) * 64 + kof];
#pragma unroll
      for (int i = 0; i < 4; ++i)
#pragma unroll
        for (int j = 0; j < 4; ++j)
          acc[i][j] = __builtin_amdgcn_mfma_f32_16x16x32_bf16(af[i], bfv[j], acc[i][j], 0, 0, 0);
    }
    __syncthreads();
  }

  // C/D layout: col = lane&15, row = (lane>>4)*4 + reg
  const int r0 = brow + wr * 64 + (lane >> 4) * 4;
  const int c0 = bcol + wc * 64 + (lane & 15);
#pragma unroll
  for (int i = 0; i < 4; ++i) {
#pragma unroll
    for (int j = 0; j < 4; ++j) {
      const int cc = c0 + j * 16;
#pragma unroll
      for (int qi = 0; qi < 4; ++qi) {
        const int rr = r0 + i * 16 + qi;
        const size_t off = (size_t)rr * N + cc;
        const float val = acc[i][j][qi];
        if (EPI == 0) {
          Cf[off] = val;
        } else if (EPI == 2) {
          Cf[off] = res[off] + val;
        } else if (EPI == 3) {
          unsigned short hh, ll;
          split2(gelu_exact(val + bias[cc]), hh, ll);
          Cb[(size_t)rr * (2 * N) + cc] = hh;
          Cb[(size_t)rr * (2 * N) + N + cc] = ll;
        } else {
          Cf[off] = res[off] + val + bias[cc];
        }
      }
    }
  }
}

// ---------------- attention v4: tanh-bounded softmax, NO online rescale ----------------
// S = 30*tanh(qk/8) is bounded in [-30,30] -> exp(S) never overflows, the diagonal
// guarantees sum >= e^-30 -> fixed-base softmax, no max tracking, no shuffle per chunk.
// grid.x = B*H*16 ; block = 256 (4 waves); block owns 32 rows, wave owns 8.
// Per 64-key half:
//   Phase A (lane=key): K regs (kq[16] f4), q broadcast; p = exp(30*tanh(s/8)); row-sum
//                       accumulated per-lane in regs; p -> LDS.
//   Phase B (lane=d):   V regs (vv[32] x2), pure FMA PV with p broadcast.
// One 6-shuffle sum reduction per row at kernel end.
// qkvf: [NTOK][3072] f32 (q|k|v). out2: [NTOK][2048] bf16 hi|lo planes.

__global__ __launch_bounds__(256, 4) void attn_kernel(
    const float* __restrict__ qkvf,
    const int* __restrict__ amask,
    unsigned short* __restrict__ out2)
{
  const int bid = blockIdx.x;
  const int rt = 15 - (bid & 15);          // heavy causal tiles dispatch first
  const int h  = (bid >> 4) & 15;
  const int b  = bid >> 8;
  const int row0 = rt * 32;

  __shared__ __align__(16) float Kst[64 * 68];      // [key][d], stride 68 dwords
  __shared__ __align__(16) float q_lds[4][8][64];   // [wave][rowk][d]
  __shared__ __align__(16) float p_lds[4][8][64];   // [wave][rowk][key]

  const int tid = threadIdx.x, lane = tid & 63, w = tid >> 6;
  const size_t base = (size_t)b * SEQ;

  // hoist q rows for this wave into LDS
#pragma unroll
  for (int k = 0; k < 8; ++k) {
    const int l = row0 + w * 8 + k;
    q_lds[w][k][lane] = qkvf[(base + l) * 3072 + h * 64 + lane];
  }

  float sum_p[8], acc_s[8];
#pragma unroll
  for (int k = 0; k < 8; ++k) { sum_p[k] = 0.f; acc_s[k] = 0.f; }

  const int nhv = (row0 >> 6) + 1;         // 64-key halves covering 0..row0+31
  for (int hf = 0; hf < nhv; ++hf) {
    const int hs = hf << 6;
    __syncthreads();                       // prev half fully consumed
#pragma unroll
    for (int it = 0; it < 4; ++it) {       // stage K half (coalesced f4)
      const int idx = it * 256 + tid;      // 0..1023 = 64 keys x 16 f4-slots
      const int i = idx >> 4, c4 = idx & 15;
      *(float4*)&Kst[i * 68 + c4 * 4] =
          *(const float4*)&qkvf[(base + hs + i) * 3072 + 1024 + h * 64 + c4 * 4];
    }
    __syncthreads();

    const int key = hs + lane;

    // ---- Phase A: scores -> p (lane = key) ----
    {
      float4 kq[16];
#pragma unroll
      for (int c4 = 0; c4 < 16; ++c4)
        kq[c4] = *(const float4*)&Kst[lane * 68 + c4 * 4];
      const int am = amask[b * SEQ + key];
#pragma unroll
      for (int k = 0; k < 8; ++k) {
        const int l = row0 + w * 8 + k;
        float4 sv = {0.f, 0.f, 0.f, 0.f};
#pragma unroll
        for (int c4 = 0; c4 < 16; ++c4) {
          const float4 qv = *(const float4*)&q_lds[w][k][c4 * 4];
          sv.x += kq[c4].x * qv.x; sv.y += kq[c4].y * qv.y;
          sv.z += kq[c4].z * qv.z; sv.w += kq[c4].w * qv.w;
        }
        const float s = (sv.x + sv.y) + (sv.z + sv.w);
        // 30*tanh(s/8) via e = exp(s/4); NaN-safe at +-inf
        const float e = __expf(s * 0.25f);
        const float S = 30.f - 60.f / (e + 1.f);
        float p = __expf(S);
        p = ((key <= l) && (am != 0)) ? p : 0.f;
        sum_p[k] += p;
        p_lds[w][k][lane] = p;
      }
    }
    __asm__ volatile("s_waitcnt lgkmcnt(0)" ::: "memory");

    // ---- Phase B: PV (lane = d), 32 keys at a time to cap VGPR ----
#pragma unroll
    for (int half32 = 0; half32 < 2; ++half32) {
      float vv[32];
#pragma unroll
      for (int j = 0; j < 32; ++j)
        vv[j] = qkvf[(base + hs + half32 * 32 + j) * 3072 + 2048 + h * 64 + lane];
#pragma unroll
      for (int k = 0; k < 8; ++k) {
        float a0 = 0.f, a1 = 0.f, a2 = 0.f, a3 = 0.f;
#pragma unroll
        for (int i4 = 0; i4 < 8; ++i4) {
          const float4 p4 = *(const float4*)&p_lds[w][k][half32 * 32 + i4 * 4];
          a0 += p4.x * vv[i4 * 4 + 0];
          a1 += p4.y * vv[i4 * 4 + 1];
          a2 += p4.z * vv[i4 * 4 + 2];
          a3 += p4.w * vv[i4 * 4 + 3];
        }
        acc_s[k] += (a0 + a1) + (a2 + a3);
      }
    }
  }

  // final: one shuffle-reduce per row for the softmax denominator
#pragma unroll
  for (int k = 0; k < 8; ++k) {
    float cs = sum_p[k];
#pragma unroll
    for (int o = 32; o; o >>= 1) cs += __shfl_xor(cs, o);
    const int l = row0 + w * 8 + k;
    const float o = acc_s[k] / cs;
    unsigned short hh, ll;
    split2(o, hh, ll);
    out2[(base + l) * 2048 + h * 64 + lane] = hh;
    out2[(base + l) * 2048 + 1024 + h * 64 + lane] = ll;
  }
}

extern "C" void kernel_launch(void* const* d_in, const int* in_sizes, int n_in,
                              void* d_out, int out_size, void* d_ws, size_t ws_size,
                              hipStream_t stream) {
  const int*   ids       = (const int*)d_in[0];
  const int*   amask     = (const int*)d_in[1];
  const float* W_vocab   = (const float*)d_in[2];
  const float* W_devocab = (const float*)d_in[3];
  const float* WQ        = (const float*)d_in[4];
  const float* WK        = (const float*)d_in[5];
  const float* WV        = (const float*)d_in[6];
  const float* W_O       = (const float*)d_in[7];
  const float* gamma1    = (const float*)d_in[8];
  const float* beta1     = (const float*)d_in[9];
  const float* gamma2    = (const float*)d_in[10];
  const float* beta2     = (const float*)d_in[11];
  const float* W_up      = (const float*)d_in[12];
  const float* b_up      = (const float*)d_in[13];
  const float* W_down    = (const float*)d_in[14];
  const float* b_down    = (const float*)d_in[15];
  const float* gamma_f   = (const float*)d_in[16];
  const float* beta_f    = (const float*)d_in[17];

  char* p = (char*)d_ws;
  auto alloc = [&](size_t bytes) { char* r = p; p += (bytes + 255) & ~(size_t)255; return r; };

  unsigned short* WQKV2 = (unsigned short*)alloc((size_t)NLAYERS * 3072 * 2048 * 2);
  unsigned short* WO2   = (unsigned short*)alloc((size_t)NLAYERS * 1024 * 2048 * 2);
  unsigned short* WUp2  = (unsigned short*)alloc((size_t)NLAYERS * 4096 * 2048 * 2);
  unsigned short* WDn2  = (unsigned short*)alloc((size_t)NLAYERS * 1024 * 8192 * 2);
  unsigned short* WDev1 = (unsigned short*)alloc((size_t)VOCAB * 1024 * 2);
  float* x    = (float*)alloc((size_t)NTOK * 1024 * 4);
  float* z1   = (float*)alloc((size_t)NTOK * 1024 * 4);
  unsigned short* u2    = (unsigned short*)alloc((size_t)NTOK * 2048 * 2);   // also v1 / xf
  float* qkvf = (float*)alloc((size_t)NTOK * 3072 * 4);
  unsigned short* attn2 = (unsigned short*)alloc((size_t)NTOK * 2048 * 2);
  unsigned short* h2    = (unsigned short*)alloc((size_t)NTOK * 8192 * 2);
  (void)ws_size; (void)in_sizes; (void)n_in; (void)out_size;

  // ---- weight prep (hi/lo split planes) ----
  cvt_qkv_split<<<2048, 256, 0, stream>>>(WQ, WK, WV, WQKV2);
  cvt_split<<<2048, 256, 0, stream>>>(W_O, WO2, (long)NLAYERS * 1024, 1024);
  transpose_cvt_split<<<dim3(4096 / 32, 1024 / 32, NLAYERS), 256, 0, stream>>>(W_up, WUp2, 1024, 4096);
  transpose_cvt_split<<<dim3(1024 / 32, 4096 / 32, NLAYERS), 256, 0, stream>>>(W_down, WDn2, 4096, 1024);
  transpose_cvt<<<dim3(VOCAB / 32, 1024 / 32, 1), 256, 0, stream>>>(W_devocab, WDev1, 1024, VOCAB);

  // ---- embedding ----
  embed_kernel<<<NTOK, 256, 0, stream>>>(ids, W_vocab, x);

  // ---- layers ----
  for (int l = 0; l < NLAYERS; ++l) {
    layernorm_split<<<NTOK, 256, 0, stream>>>(x, gamma1 + l * 1024, beta1 + l * 1024, u2);
    // fused QKV (split-3, f32 out): [4096,3072]
    gemm_bt<0, 3><<<dim3(3072 / 128, NTOK / 128), 256, 0, stream>>>(
        u2, WQKV2 + (size_t)l * 3072 * 2048, qkvf, nullptr, nullptr, nullptr,
        NTOK, 3072, 1024);
    attn_kernel<<<BATCH * NHEADS * 16, 256, 0, stream>>>(qkvf, amask, attn2);
    // z1 = x + attn @ W_O^T
    gemm_bt<2, 3><<<dim3(1024 / 128, NTOK / 128), 256, 0, stream>>>(
        attn2, WO2 + (size_t)l * 1024 * 2048, z1, nullptr, nullptr, x,
        NTOK, 1024, 1024);
    layernorm_split<<<NTOK, 256, 0, stream>>>(z1, gamma2 + l * 1024, beta2 + l * 1024, u2);
    // h = gelu(v1 @ W_up + b_up), hi/lo out
    gemm_bt<3, 3><<<dim3(4096 / 128, NTOK / 128), 256, 0, stream>>>(
        u2, WUp2 + (size_t)l * 4096 * 2048, nullptr, h2, b_up + l * 4096, nullptr,
        NTOK, 4096, 1024);
    // x = z1 + h @ W_down + b_down
    gemm_bt<4, 3><<<dim3(1024 / 128, NTOK / 128), 256, 0, stream>>>(
        h2, WDn2 + (size_t)l * 1024 * 8192, x, nullptr, b_down + l * 1024, z1,
        NTOK, 1024, 4096);
  }

  // ---- final LN + devocab (split-2: x hi/lo, W hi only) ----
  layernorm_split<<<NTOK, 256, 0, stream>>>(x, gamma_f, beta_f, u2);
  gemm_bt<0, 2><<<dim3(VOCAB / 128, NTOK / 128), 256, 0, stream>>>(
      u2, WDev1, (float*)d_out, nullptr, nullptr, nullptr,
      NTOK, VOCAB, 1024);
}

// Round 10
// 16130.630 us; speedup vs baseline: 2.3256x; 1.0746x over previous
//
#include <hip/hip_runtime.h>
#include <math.h>

#define D_MODEL 1024
#define NHEADS 16
#define DHEAD 64
#define NLAYERS 12
#define VOCAB 32000
#define BATCH 8
#define SEQ 512
#define NTOK (BATCH*SEQ)   // 4096

using short8 = __attribute__((ext_vector_type(8))) short;
using fx4    = __attribute__((ext_vector_type(4))) float;

#define GLL16(g, l) __builtin_amdgcn_global_load_lds( \
    (const __attribute__((address_space(1))) unsigned int*)(g), \
    (__attribute__((address_space(3))) unsigned int*)(l), 16, 0, 0)

__device__ __forceinline__ unsigned short f2bf(float f) {
  union { float f; unsigned u; } v; v.f = f;
  unsigned r = v.u + 0x7FFFu + ((v.u >> 16) & 1u);
  return (unsigned short)(r >> 16);
}
__device__ __forceinline__ float bf2f(unsigned short u) {
  union { unsigned u; float f; } v; v.u = ((unsigned)u) << 16;
  return v.f;
}
__device__ __forceinline__ void split2(float x, unsigned short& h, unsigned short& l) {
  h = f2bf(x);
  l = f2bf(x - bf2f(h));
}
__device__ __forceinline__ float gelu_exact(float x) {
  return 0.5f * x * (1.f + erff(x * 0.70710678118654752f));
}

// ---------------- weight conversion (hi/lo split planes) ----------------

__global__ __launch_bounds__(256) void cvt_qkv_split(const float* __restrict__ WQ,
    const float* __restrict__ WK, const float* __restrict__ WV,
    unsigned short* __restrict__ out)
{
  const long total = 12L * 3072 * 256;     // float4 units
  const long stride = (long)gridDim.x * blockDim.x;
  for (long t = (long)blockIdx.x * blockDim.x + threadIdx.x; t < total; t += stride) {
    const long layer = t / (3072L * 256);
    const long rem = t - layer * (3072L * 256);
    const int n = (int)(rem >> 8);
    const int k4 = (int)(rem & 255);
    const float* src;
    if (n < 1024)       src = WQ + ((size_t)layer * 1024 + n) * 1024;
    else if (n < 2048)  src = WK + ((size_t)layer * 1024 + (n - 1024)) * 1024;
    else                src = WV + ((size_t)layer * 1024 + (n - 2048)) * 1024;
    const float4 v = *(const float4*)(src + k4 * 4);
    ushort4 h, l; unsigned short a, b;
    split2(v.x, a, b); h.x = a; l.x = b;
    split2(v.y, a, b); h.y = a; l.y = b;
    split2(v.z, a, b); h.z = a; l.z = b;
    split2(v.w, a, b); h.w = a; l.w = b;
    unsigned short* dst = out + ((size_t)layer * 3072 + n) * 2048 + k4 * 4;
    *(ushort4*)dst = h;
    *(ushort4*)(dst + 1024) = l;
  }
}

__global__ __launch_bounds__(256) void cvt_split(const float* __restrict__ in,
    unsigned short* __restrict__ out, long rows, int K)
{
  const int K4 = K >> 2;
  const long total = rows * K4;
  const long stride = (long)gridDim.x * blockDim.x;
  for (long t = (long)blockIdx.x * blockDim.x + threadIdx.x; t < total; t += stride) {
    const long r = t / K4;
    const int k4 = (int)(t - r * K4);
    const float4 v = *(const float4*)(in + r * K + k4 * 4);
    ushort4 h, l; unsigned short a, b;
    split2(v.x, a, b); h.x = a; l.x = b;
    split2(v.y, a, b); h.y = a; l.y = b;
    split2(v.z, a, b); h.z = a; l.z = b;
    split2(v.w, a, b); h.w = a; l.w = b;
    unsigned short* dst = out + r * 2 * K + k4 * 4;
    *(ushort4*)dst = h;
    *(ushort4*)(dst + K) = l;
  }
}

__global__ __launch_bounds__(256) void transpose_cvt_split(const float* __restrict__ in,
    unsigned short* __restrict__ out, int R, int C)
{
  __shared__ float tile[32][33];
  in  += (size_t)blockIdx.z * R * C;
  out += (size_t)blockIdx.z * 2 * R * C;
  const int r0 = blockIdx.y * 32, c0 = blockIdx.x * 32;
  const int tr = threadIdx.x >> 5, tc = threadIdx.x & 31;
#pragma unroll
  for (int i = 0; i < 4; ++i)
    tile[tr + i * 8][tc] = in[(size_t)(r0 + tr + i * 8) * C + c0 + tc];
  __syncthreads();
#pragma unroll
  for (int i = 0; i < 4; ++i) {
    unsigned short h, l;
    split2(tile[tc][tr + i * 8], h, l);
    const size_t o = (size_t)(c0 + tr + i * 8) * 2 * R + r0 + tc;
    out[o] = h;
    out[o + R] = l;
  }
}

__global__ __launch_bounds__(256) void transpose_cvt(const float* __restrict__ in,
    unsigned short* __restrict__ out, int R, int C)
{
  __shared__ float tile[32][33];
  const int r0 = blockIdx.y * 32, c0 = blockIdx.x * 32;
  const int tr = threadIdx.x >> 5, tc = threadIdx.x & 31;
#pragma unroll
  for (int i = 0; i < 4; ++i)
    tile[tr + i * 8][tc] = in[(size_t)(r0 + tr + i * 8) * C + c0 + tc];
  __syncthreads();
#pragma unroll
  for (int i = 0; i < 4; ++i)
    out[(size_t)(c0 + tr + i * 8) * R + r0 + tc] = f2bf(tile[tc][tr + i * 8]);
}

// ---------------- embedding + positional ----------------

__global__ __launch_bounds__(256) void embed_kernel(const int* __restrict__ ids,
    const float* __restrict__ Wv, float* __restrict__ x)
{
  const int t = blockIdx.x;
  const int id = ids[t];
  const int l = t & (SEQ - 1);
  const float pos = (float)l;
  const int d0 = threadIdx.x * 4;
  const float i0 = (float)(d0 >> 1);
  const float f0 = expf(-0.017988946039016f * i0);
  const float f1 = expf(-0.017988946039016f * (i0 + 1.f));
  const float a0 = pos * f0, a1 = pos * f1;
  float4 v;
  v.x = Wv[(size_t)(d0 + 0) * VOCAB + id] + sinf(a0);
  v.y = Wv[(size_t)(d0 + 1) * VOCAB + id] + cosf(a0);
  v.z = Wv[(size_t)(d0 + 2) * VOCAB + id] + sinf(a1);
  v.w = Wv[(size_t)(d0 + 3) * VOCAB + id] + cosf(a1);
  ((float4*)(x + (size_t)t * 1024))[threadIdx.x] = v;
}

// ---------------- layernorm (f32 in -> hi/lo bf16 planes out, stride 2048) ----------------

__global__ __launch_bounds__(256) void layernorm_split(const float* __restrict__ x,
    const float* __restrict__ g, const float* __restrict__ be,
    unsigned short* __restrict__ out)
{
  const int row = blockIdx.x;
  const float4 v = ((const float4*)(x + (size_t)row * 1024))[threadIdx.x];
  float s = v.x + v.y + v.z + v.w;
  float q = v.x * v.x + v.y * v.y + v.z * v.z + v.w * v.w;
#pragma unroll
  for (int o = 32; o; o >>= 1) { s += __shfl_xor(s, o); q += __shfl_xor(q, o); }
  __shared__ float ss[4], qq[4];
  const int w = threadIdx.x >> 6;
  if ((threadIdx.x & 63) == 0) { ss[w] = s; qq[w] = q; }
  __syncthreads();
  s = ss[0] + ss[1] + ss[2] + ss[3];
  q = qq[0] + qq[1] + qq[2] + qq[3];
  const float mean = s * (1.f / 1024.f);
  const float var = q * (1.f / 1024.f) - mean * mean;
  const float rstd = rsqrtf(var + 1e-5f);
  const float4 gv = ((const float4*)g)[threadIdx.x];
  const float4 bv = ((const float4*)be)[threadIdx.x];
  float4 y;
  y.x = (v.x - mean) * rstd * gv.x + bv.x;
  y.y = (v.y - mean) * rstd * gv.y + bv.y;
  y.z = (v.z - mean) * rstd * gv.z + bv.z;
  y.w = (v.w - mean) * rstd * gv.w + bv.w;
  ushort4 h4, l4; unsigned short a, b;
  split2(y.x, a, b); h4.x = a; l4.x = b;
  split2(y.y, a, b); h4.y = a; l4.y = b;
  split2(y.z, a, b); h4.z = a; l4.z = b;
  split2(y.w, a, b); h4.w = a; l4.w = b;
  unsigned short* dst = out + (size_t)row * 2048 + threadIdx.x * 4;
  *(ushort4*)dst = h4;
  *(ushort4*)(dst + 1024) = l4;
}

// ---------------- split GEMM: C[M,N] = A[M,K] * B[N,K]^T, near-f32 precision ----------------
// global_load_lds width-16 staging + XOR slot-swizzle (rule #21: linear LDS dest,
// inverse-swizzled GLOBAL source, swizzled READ). LDS tile [128 rows][8 slots of 16B];
// slot' = slot ^ (row&7). Read rows R have R&7 == lane&7 for every fragment.

template<int EPI, int SPLIT>
__global__ __launch_bounds__(256) void gemm_bt(
    const unsigned short* __restrict__ A, const unsigned short* __restrict__ B,
    float* __restrict__ Cf, unsigned short* __restrict__ Cb,
    const float* __restrict__ bias, const float* __restrict__ res,
    int M, int N, int K)
{
  __shared__ __align__(16) unsigned short As[128 * 64];
  __shared__ __align__(16) unsigned short Bs[128 * 64];
  const int tid = threadIdx.x;
  const int lane = tid & 63, w = tid >> 6;
  const int wr = w >> 1, wc = w & 1;
  const int brow = blockIdx.y * 128, bcol = blockIdx.x * 128;

  const int SA = 2 * K;                         // A always hi/lo
  const int SB = (SPLIT == 3) ? 2 * K : K;
  const int KEFF = SPLIT * K;
  fx4 acc[4][4];
  const fx4 zero = {0.f, 0.f, 0.f, 0.f};
#pragma unroll
  for (int i = 0; i < 4; ++i)
#pragma unroll
    for (int j = 0; j < 4; ++j) acc[i][j] = zero;

  const unsigned short* Ab = A + (size_t)brow * SA;
  const unsigned short* Bb = B + (size_t)bcol * SB;

  for (int k0 = 0; k0 < KEFF; k0 += 64) {
    int ka, kb;
    if (SPLIT == 3) {
      ka = (k0 < 2 * K) ? k0 : k0 - 2 * K;      // hi | lo | hi
      kb = (k0 < K) ? k0 : k0 - K;              // hi | hi | lo
    } else {
      ka = k0;                                  // hi | lo
      kb = (k0 < K) ? k0 : k0 - K;              // hi | hi
    }
    const unsigned short* Aseg = Ab + ka;
    const unsigned short* Bseg = Bb + kb;
#pragma unroll
    for (int it = 0; it < 4; ++it) {
      const int idx = it * 256 + tid;          // 0..1023
      const int r = idx >> 3;                  // tile row 0..127
      // source slot pre-swizzled so LDS slot (r, s) holds global slot s^(r&7)
      const int c = ((idx & 7) ^ (r & 7)) * 8; // col in shorts
      GLL16(&Aseg[(size_t)r * SA + c], &As[idx * 8]);
      GLL16(&Bseg[(size_t)r * SB + c], &Bs[idx * 8]);
    }
    __syncthreads();   // drains vmcnt (global_load_lds) before ds_read
#pragma unroll
    for (int kk = 0; kk < 2; ++kk) {
      short8 af[4], bfv[4];
      // logical slot for this lane: kk*4 + (lane>>4); swizzle with row parity (= lane&7)
      const int slot = ((kk * 4 + (lane >> 4)) ^ (lane & 7)) * 8;
#pragma unroll
      for (int f = 0; f < 4; ++f)
        af[f] = *(const short8*)&As[(wr * 64 + f * 16 + (lane & 15)) * 64 + slot];
#pragma unroll
      for (int f = 0; f < 4; ++f)
        bfv[f] = *(const short8*)&Bs[(wc * 64 + f * 16 + (lane & 15)) * 64 + slot];
#pragma unroll
      for (int i = 0; i < 4; ++i)
#pragma unroll
        for (int j = 0; j < 4; ++j)
          acc[i][j] = __builtin_amdgcn_mfma_f32_16x16x32_bf16(af[i], bfv[j], acc[i][j], 0, 0, 0);
    }
    __syncthreads();
  }

  // C/D layout: col = lane&15, row = (lane>>4)*4 + reg
  const int r0 = brow + wr * 64 + (lane >> 4) * 4;
  const int c0 = bcol + wc * 64 + (lane & 15);
#pragma unroll
  for (int i = 0; i < 4; ++i) {
#pragma unroll
    for (int j = 0; j < 4; ++j) {
      const int cc = c0 + j * 16;
#pragma unroll
      for (int qi = 0; qi < 4; ++qi) {
        const int rr = r0 + i * 16 + qi;
        const size_t off = (size_t)rr * N + cc;
        const float val = acc[i][j][qi];
        if (EPI == 0) {
          Cf[off] = val;
        } else if (EPI == 2) {
          Cf[off] = res[off] + val;
        } else if (EPI == 3) {
          unsigned short hh, ll;
          split2(gelu_exact(val + bias[cc]), hh, ll);
          Cb[(size_t)rr * (2 * N) + cc] = hh;
          Cb[(size_t)rr * (2 * N) + N + cc] = ll;
        } else {
          Cf[off] = res[off] + val + bias[cc];
        }
      }
    }
  }
}

// ---------------- attention v4: tanh-bounded softmax, NO online rescale ----------------
// (unchanged from round 8)

__global__ __launch_bounds__(256, 4) void attn_kernel(
    const float* __restrict__ qkvf,
    const int* __restrict__ amask,
    unsigned short* __restrict__ out2)
{
  const int bid = blockIdx.x;
  const int rt = 15 - (bid & 15);          // heavy causal tiles dispatch first
  const int h  = (bid >> 4) & 15;
  const int b  = bid >> 8;
  const int row0 = rt * 32;

  __shared__ __align__(16) float Kst[64 * 68];      // [key][d], stride 68 dwords
  __shared__ __align__(16) float q_lds[4][8][64];   // [wave][rowk][d]
  __shared__ __align__(16) float p_lds[4][8][64];   // [wave][rowk][key]

  const int tid = threadIdx.x, lane = tid & 63, w = tid >> 6;
  const size_t base = (size_t)b * SEQ;

  // hoist q rows for this wave into LDS
#pragma unroll
  for (int k = 0; k < 8; ++k) {
    const int l = row0 + w * 8 + k;
    q_lds[w][k][lane] = qkvf[(base + l) * 3072 + h * 64 + lane];
  }

  float sum_p[8], acc_s[8];
#pragma unroll
  for (int k = 0; k < 8; ++k) { sum_p[k] = 0.f; acc_s[k] = 0.f; }

  const int nhv = (row0 >> 6) + 1;         // 64-key halves covering 0..row0+31
  for (int hf = 0; hf < nhv; ++hf) {
    const int hs = hf << 6;
    __syncthreads();                       // prev half fully consumed
#pragma unroll
    for (int it = 0; it < 4; ++it) {       // stage K half (coalesced f4)
      const int idx = it * 256 + tid;      // 0..1023 = 64 keys x 16 f4-slots
      const int i = idx >> 4, c4 = idx & 15;
      *(float4*)&Kst[i * 68 + c4 * 4] =
          *(const float4*)&qkvf[(base + hs + i) * 3072 + 1024 + h * 64 + c4 * 4];
    }
    __syncthreads();

    const int key = hs + lane;

    // ---- Phase A: scores -> p (lane = key) ----
    {
      float4 kq[16];
#pragma unroll
      for (int c4 = 0; c4 < 16; ++c4)
        kq[c4] = *(const float4*)&Kst[lane * 68 + c4 * 4];
      const int am = amask[b * SEQ + key];
#pragma unroll
      for (int k = 0; k < 8; ++k) {
        const int l = row0 + w * 8 + k;
        float4 sv = {0.f, 0.f, 0.f, 0.f};
#pragma unroll
        for (int c4 = 0; c4 < 16; ++c4) {
          const float4 qv = *(const float4*)&q_lds[w][k][c4 * 4];
          sv.x += kq[c4].x * qv.x; sv.y += kq[c4].y * qv.y;
          sv.z += kq[c4].z * qv.z; sv.w += kq[c4].w * qv.w;
        }
        const float s = (sv.x + sv.y) + (sv.z + sv.w);
        // 30*tanh(s/8) via e = exp(s/4); NaN-safe at +-inf
        const float e = __expf(s * 0.25f);
        const float S = 30.f - 60.f / (e + 1.f);
        float p = __expf(S);
        p = ((key <= l) && (am != 0)) ? p : 0.f;
        sum_p[k] += p;
        p_lds[w][k][lane] = p;
      }
    }
    __asm__ volatile("s_waitcnt lgkmcnt(0)" ::: "memory");

    // ---- Phase B: PV (lane = d), 32 keys at a time to cap VGPR ----
#pragma unroll
    for (int half32 = 0; half32 < 2; ++half32) {
      float vv[32];
#pragma unroll
      for (int j = 0; j < 32; ++j)
        vv[j] = qkvf[(base + hs + half32 * 32 + j) * 3072 + 2048 + h * 64 + lane];
#pragma unroll
      for (int k = 0; k < 8; ++k) {
        float a0 = 0.f, a1 = 0.f, a2 = 0.f, a3 = 0.f;
#pragma unroll
        for (int i4 = 0; i4 < 8; ++i4) {
          const float4 p4 = *(const float4*)&p_lds[w][k][half32 * 32 + i4 * 4];
          a0 += p4.x * vv[i4 * 4 + 0];
          a1 += p4.y * vv[i4 * 4 + 1];
          a2 += p4.z * vv[i4 * 4 + 2];
          a3 += p4.w * vv[i4 * 4 + 3];
        }
        acc_s[k] += (a0 + a1) + (a2 + a3);
      }
    }
  }

  // final: one shuffle-reduce per row for the softmax denominator
#pragma unroll
  for (int k = 0; k < 8; ++k) {
    float cs = sum_p[k];
#pragma unroll
    for (int o = 32; o; o >>= 1) cs += __shfl_xor(cs, o);
    const int l = row0 + w * 8 + k;
    const float o = acc_s[k] / cs;
    unsigned short hh, ll;
    split2(o, hh, ll);
    out2[(base + l) * 2048 + h * 64 + lane] = hh;
    out2[(base + l) * 2048 + 1024 + h * 64 + lane] = ll;
  }
}

extern "C" void kernel_launch(void* const* d_in, const int* in_sizes, int n_in,
                              void* d_out, int out_size, void* d_ws, size_t ws_size,
                              hipStream_t stream) {
  const int*   ids       = (const int*)d_in[0];
  const int*   amask     = (const int*)d_in[1];
  const float* W_vocab   = (const float*)d_in[2];
  const float* W_devocab = (const float*)d_in[3];
  const float* WQ        = (const float*)d_in[4];
  const float* WK        = (const float*)d_in[5];
  const float* WV        = (const float*)d_in[6];
  const float* W_O       = (const float*)d_in[7];
  const float* gamma1    = (const float*)d_in[8];
  const float* beta1     = (const float*)d_in[9];
  const float* gamma2    = (const float*)d_in[10];
  const float* beta2     = (const float*)d_in[11];
  const float* W_up      = (const float*)d_in[12];
  const float* b_up      = (const float*)d_in[13];
  const float* W_down    = (const float*)d_in[14];
  const float* b_down    = (const float*)d_in[15];
  const float* gamma_f   = (const float*)d_in[16];
  const float* beta_f    = (const float*)d_in[17];

  char* p = (char*)d_ws;
  auto alloc = [&](size_t bytes) { char* r = p; p += (bytes + 255) & ~(size_t)255; return r; };

  unsigned short* WQKV2 = (unsigned short*)alloc((size_t)NLAYERS * 3072 * 2048 * 2);
  unsigned short* WO2   = (unsigned short*)alloc((size_t)NLAYERS * 1024 * 2048 * 2);
  unsigned short* WUp2  = (unsigned short*)alloc((size_t)NLAYERS * 4096 * 2048 * 2);
  unsigned short* WDn2  = (unsigned short*)alloc((size_t)NLAYERS * 1024 * 8192 * 2);
  unsigned short* WDev1 = (unsigned short*)alloc((size_t)VOCAB * 1024 * 2);
  float* x    = (float*)alloc((size_t)NTOK * 1024 * 4);
  float* z1   = (float*)alloc((size_t)NTOK * 1024 * 4);
  unsigned short* u2    = (unsigned short*)alloc((size_t)NTOK * 2048 * 2);   // also v1 / xf
  float* qkvf = (float*)alloc((size_t)NTOK * 3072 * 4);
  unsigned short* attn2 = (unsigned short*)alloc((size_t)NTOK * 2048 * 2);
  unsigned short* h2    = (unsigned short*)alloc((size_t)NTOK * 8192 * 2);
  (void)ws_size; (void)in_sizes; (void)n_in; (void)out_size;

  // ---- weight prep (hi/lo split planes) ----
  cvt_qkv_split<<<2048, 256, 0, stream>>>(WQ, WK, WV, WQKV2);
  cvt_split<<<2048, 256, 0, stream>>>(W_O, WO2, (long)NLAYERS * 1024, 1024);
  transpose_cvt_split<<<dim3(4096 / 32, 1024 / 32, NLAYERS), 256, 0, stream>>>(W_up, WUp2, 1024, 4096);
  transpose_cvt_split<<<dim3(1024 / 32, 4096 / 32, NLAYERS), 256, 0, stream>>>(W_down, WDn2, 4096, 1024);
  transpose_cvt<<<dim3(VOCAB / 32, 1024 / 32, 1), 256, 0, stream>>>(W_devocab, WDev1, 1024, VOCAB);

  // ---- embedding ----
  embed_kernel<<<NTOK, 256, 0, stream>>>(ids, W_vocab, x);

  // ---- layers ----
  for (int l = 0; l < NLAYERS; ++l) {
    layernorm_split<<<NTOK, 256, 0, stream>>>(x, gamma1 + l * 1024, beta1 + l * 1024, u2);
    // fused QKV (split-3, f32 out): [4096,3072]
    gemm_bt<0, 3><<<dim3(3072 / 128, NTOK / 128), 256, 0, stream>>>(
        u2, WQKV2 + (size_t)l * 3072 * 2048, qkvf, nullptr, nullptr, nullptr,
        NTOK, 3072, 1024);
    attn_kernel<<<BATCH * NHEADS * 16, 256, 0, stream>>>(qkvf, amask, attn2);
    // z1 = x + attn @ W_O^T
    gemm_bt<2, 3><<<dim3(1024 / 128, NTOK / 128), 256, 0, stream>>>(
        attn2, WO2 + (size_t)l * 1024 * 2048, z1, nullptr, nullptr, x,
        NTOK, 1024, 1024);
    layernorm_split<<<NTOK, 256, 0, stream>>>(z1, gamma2 + l * 1024, beta2 + l * 1024, u2);
    // h = gelu(v1 @ W_up + b_up), hi/lo out
    gemm_bt<3, 3><<<dim3(4096 / 128, NTOK / 128), 256, 0, stream>>>(
        u2, WUp2 + (size_t)l * 4096 * 2048, nullptr, h2, b_up + l * 4096, nullptr,
        NTOK, 4096, 1024);
    // x = z1 + h @ W_down + b_down
    gemm_bt<4, 3><<<dim3(1024 / 128, NTOK / 128), 256, 0, stream>>>(
        h2, WDn2 + (size_t)l * 1024 * 8192, x, nullptr, b_down + l * 1024, z1,
        NTOK, 1024, 4096);
  }

  // ---- final LN + devocab (split-2: x hi/lo, W hi only) ----
  layernorm_split<<<NTOK, 256, 0, stream>>>(x, gamma_f, beta_f, u2);
  gemm_bt<0, 2><<<dim3(VOCAB / 128, NTOK / 128), 256, 0, stream>>>(
      u2, WDev1, (float*)d_out, nullptr, nullptr, nullptr,
      NTOK, VOCAB, 1024);
}